// Round 2
// baseline (348.186 us; speedup 1.0000x reference)
//
#include <hip/hip_runtime.h>

#define NB 512
#define NN 256
#define EPG 8192
#define FINC 128

typedef float f32x4 __attribute__((ext_vector_type(4)));

__device__ __forceinline__ float bf2f(unsigned short u) {
  union { unsigned int i; float f; } x; x.i = ((unsigned int)u) << 16; return x.f;
}
__device__ __forceinline__ unsigned short f2bf(float f) {
  union { float f; unsigned int i; } x; x.f = f;
  unsigned int r = x.i + 0x7fffu + ((x.i >> 16) & 1u);
  return (unsigned short)(r >> 16);
}

struct Params {
  const void* x; const void* ei;
  const void *wl1, *bl1, *wr1, *br1, *wro1, *wp, *bp;
  const void *wr2, *br2, *wro2, *wl2, *bl2, *wl3, *bl3;
  float* out; float* ws;
};

// dtype probes (block-uniform). BF: W_rel1 ~ N(0,0.177) — genuine bf16 ushorts
// have exponent field in (96,132) essentially always; fp32 low-half ushorts are
// mantissa garbage (uniform exponent -> ~14% sane). I64: int32 view of
// edge_index at element EPG is graph-1 src (values in [256,512)) iff int32;
// int64 data there shows (val<256, 0) pairs.
__device__ __forceinline__ bool detect_bf16(const void* p) {
  const unsigned short* pw = (const unsigned short*)p;
  int sane = 0;
  for (int i = 0; i < 64; ++i) {
    unsigned e = (pw[i] >> 7) & 0xFFu;
    sane += (e > 96u && e < 132u) ? 1 : 0;
  }
  return sane >= 56;
}
__device__ __forceinline__ bool detect_i64(const void* p) {
  const int* pi = (const int*)p + EPG;
  int ok = 0;
  for (int i = 0; i < 32; ++i) ok += (pi[i] >= 256 && pi[i] < 512) ? 1 : 0;
  return ok < 24;
}
__device__ __forceinline__ float ldf(const void* p, int i, bool bf) {
  return bf ? bf2f(((const unsigned short*)p)[i]) : ((const float*)p)[i];
}

// ---- dynamic LDS layout (bytes) ----
// region0 [0, 66560):  x staged as bf16 (row stride 260B) -> adj u8 col-major
//                      [v][u] (stride 260B) -> small tail buffers + FG weights
// H0     [66560, 103424): h0 f32 stride 36f; later rel1f/root1f/brel1f; later tA stride 20f
// H1     [103424,140288): lin1f+blin1f; later agg/h1 f32 stride 36f
// S      [140288,160768): s f32 stride 20f
// SC     [160768,162944): poolf(512f) bpoolf(16f) scr(16f)
#define SMEM_TOTAL 162944

__device__ __forceinline__ float block_sum(float v, float* scr, int t) {
  #pragma unroll
  for (int o = 32; o > 0; o >>= 1) v += __shfl_xor(v, o, 64);
  __syncthreads();
  if ((t & 63) == 0) scr[t >> 6] = v;
  __syncthreads();
  return scr[0] + scr[1] + scr[2] + scr[3];
}

__global__ __launch_bounds__(256, 1) void mincut_main(Params P) {
  extern __shared__ char smem[];
  const int t = threadIdx.x;
  const int b = blockIdx.x;

  const bool BF  = detect_bf16(P.wr1);
  const bool I64 = detect_i64(P.ei);

  float* h0buf  = (float*)(smem + 66560);            // stride 36 f
  float* rel1f  = (float*)(smem + 66560);            // after pass1
  float* root1f = (float*)(smem + 66560 + 4096);
  float* brel1f = (float*)(smem + 66560 + 8192);
  float* tabuf  = (float*)(smem + 66560);            // after stage C/D, stride 20 f
  float* aggbuf = (float*)(smem + 103424);           // agg then h1, stride 36 f
  float* lin1f  = (float*)(smem + 103424);
  float* blin1f = (float*)(smem + 103424 + 16384);
  float* sbuf   = (float*)(smem + 140288);           // stride 20 f
  float* poolf  = (float*)(smem + 160768);
  float* bpoolf = (float*)(smem + 160768 + 2048);
  float* scr    = (float*)(smem + 160768 + 2112);
  // region0 tail (valid only after adjacency is dead)
  float* pbuf   = (float*)(smem);            // 512 f
  float* oadjb  = (float*)(smem + 2048);     // 256 f
  float* ssb    = (float*)(smem + 3072);     // 256 f
  float* qbuf   = (float*)(smem + 4096);     // 512 f
  float* ddb    = (float*)(smem + 6144);     // 16 f
  float* h2b    = (float*)(smem + 6208);     // 512 f
  float* rb     = (float*)(smem + 8256);     // 32 f
  float* yb     = (float*)(smem + 8384);     // 32 f
  float* lgb    = (float*)(smem + 8512);     // 12 f
  float* degb   = (float*)(smem + 12288);    // 256 f
  float* rel2f  = (float*)(smem + 16384);
  float* brel2f = (float*)(smem + 20480);
  float* root2f = (float*)(smem + 20608);
  float* lin2f  = (float*)(smem + 24704);
  float* blin2f = (float*)(smem + 28800);
  float* lin3f  = (float*)(smem + 28928);
  float* blin3f = (float*)(smem + 30208);

  // ---- P0: stage lin1/pool weights (as f32) + x (as bf16, padded rows) ----
  for (int i = t; i < 4096; i += 256) lin1f[i] = ldf(P.wl1, i, BF);
  if (t < 32) blin1f[t] = ldf(P.bl1, t, BF);
  for (int i = t; i < 512; i += 256) poolf[i] = ldf(P.wp, i, BF);
  if (t < 16) bpoolf[t] = ldf(P.bp, t, BF);
  if (BF) {
    const unsigned short* gx = (const unsigned short*)P.x + (size_t)b * (NN * FINC);
    #pragma unroll
    for (int it = 0; it < 16; ++it) {
      int g = (it * 256 + t) * 8;
      int n = g >> 7, k = g & 127;
      uint4 val = *(const uint4*)(gx + g);
      unsigned int* dst = (unsigned int*)(smem + n * 260 + k * 2);
      dst[0] = val.x; dst[1] = val.y; dst[2] = val.z; dst[3] = val.w;
    }
  } else {
    const float* gx = (const float*)P.x + (size_t)b * (NN * FINC);
    #pragma unroll
    for (int it = 0; it < 16; ++it) {
      int g = (it * 256 + t) * 8;
      int n = g >> 7, k = g & 127;
      float4 v0 = *(const float4*)(gx + g);
      float4 v1 = *(const float4*)(gx + g + 4);
      unsigned int* dst = (unsigned int*)(smem + n * 260 + k * 2);
      dst[0] = (unsigned)f2bf(v0.x) | ((unsigned)f2bf(v0.y) << 16);
      dst[1] = (unsigned)f2bf(v0.z) | ((unsigned)f2bf(v0.w) << 16);
      dst[2] = (unsigned)f2bf(v1.x) | ((unsigned)f2bf(v1.y) << 16);
      dst[3] = (unsigned)f2bf(v1.z) | ((unsigned)f2bf(v1.w) << 16);
    }
  }
  __syncthreads();

  // ---- P1: h0 = x @ W_lin1 + b  (thread t = node t) ----
  f32x4 h0v[8];
  {
    #pragma unroll
    for (int q = 0; q < 8; ++q) h0v[q] = *(const f32x4*)(blin1f + q * 4);
    const unsigned short* xrow = (const unsigned short*)(smem + t * 260);
    for (int k = 0; k < FINC; ++k) {
      float xv = bf2f(xrow[k]);
      const f32x4* wr = (const f32x4*)(lin1f + k * 32);
      #pragma unroll
      for (int q = 0; q < 8; ++q) h0v[q] += xv * wr[q];
    }
    float* dst = h0buf + t * 36;
    #pragma unroll
    for (int q = 0; q < 8; ++q) *(f32x4*)(dst + q * 4) = h0v[q];
  }
  __syncthreads();

  // ---- P2: zero adjacency region ----
  for (int i = t; i < 16640; i += 256) ((unsigned int*)smem)[i] = 0u;
  __syncthreads();

  // ---- P3: build u8 adjacency, column-major [v][u], packed-byte atomics ----
  if (I64) {
    const long long* es = (const long long*)P.ei + (size_t)b * EPG;
    const long long* ed = (const long long*)P.ei + (size_t)NB * EPG + (size_t)b * EPG;
    #pragma unroll 4
    for (int i2 = 0; i2 < EPG / 256; ++i2) {
      int e = i2 * 256 + t;
      int u = ((int)es[e]) & 255;
      int v = ((int)ed[e]) & 255;
      unsigned idx = (unsigned)(v * 260 + u);
      atomicAdd((unsigned int*)(smem + (idx & ~3u)), 1u << ((idx & 3u) * 8u));
    }
  } else {
    const int* es = (const int*)P.ei + (size_t)b * EPG;
    const int* ed = (const int*)P.ei + (size_t)NB * EPG + (size_t)b * EPG;
    #pragma unroll 4
    for (int i2 = 0; i2 < EPG / 256; ++i2) {
      int e = i2 * 256 + t;
      int u = es[e] & 255;
      int v = ed[e] & 255;
      unsigned idx = (unsigned)(v * 260 + u);
      atomicAdd((unsigned int*)(smem + (idx & ~3u)), 1u << ((idx & 3u) * 8u));
    }
  }
  __syncthreads();

  // ---- P4: pass1  agg = A @ h0 (+ degree); thread = 4 rows x 8 ch ----
  const int rg = t >> 2, cg = t & 3;
  float dg[4] = {0.f, 0.f, 0.f, 0.f};
  {
    f32x4 acc[4][2] = {};
    for (int v = 0; v < 256; ++v) {
      unsigned w = *(const unsigned int*)(smem + v * 260 + rg * 4);
      const f32x4* hv = (const f32x4*)(h0buf + v * 36 + cg * 8);
      f32x4 ha = hv[0], hb = hv[1];
      #pragma unroll
      for (int r = 0; r < 4; ++r) {
        float cf = (float)((w >> (8 * r)) & 255u);
        dg[r] += cf;
        acc[r][0] += cf * ha;
        acc[r][1] += cf * hb;
      }
    }
    #pragma unroll
    for (int r = 0; r < 4; ++r) {
      float* dstp = aggbuf + (4 * rg + r) * 36 + cg * 8;
      *(f32x4*)(dstp) = acc[r][0];
      *(f32x4*)(dstp + 4) = acc[r][1];
    }
  }
  __syncthreads();

  // ---- P4.5: conv1 weights into dead h0 region ----
  for (int i = t; i < 1024; i += 256) rel1f[i] = ldf(P.wr1, i, BF);
  for (int i = t; i < 1024; i += 256) root1f[i] = ldf(P.wro1, i, BF);
  if (t < 32) brel1f[t] = ldf(P.br1, t, BF);
  __syncthreads();

  // ---- Stage C: h1 = agg @ W_rel1 + b_rel1 + h0 @ W_root1 (thread t = node t) ----
  f32x4 h1v[8];
  {
    f32x4 aggv[8];
    const float* arow = aggbuf + t * 36;
    #pragma unroll
    for (int q = 0; q < 8; ++q) aggv[q] = *(const f32x4*)(arow + q * 4);
    #pragma unroll
    for (int q = 0; q < 8; ++q) h1v[q] = *(const f32x4*)(brel1f + q * 4);
    #pragma unroll
    for (int k = 0; k < 32; ++k) {
      float av = aggv[k >> 2][k & 3];
      float bv = h0v[k >> 2][k & 3];
      const f32x4* wr = (const f32x4*)(rel1f + k * 32);
      const f32x4* wo = (const f32x4*)(root1f + k * 32);
      #pragma unroll
      for (int q = 0; q < 8; ++q) h1v[q] += av * wr[q] + bv * wo[q];
    }
    float* dsth1 = aggbuf + t * 36;   // overwrite own agg row (only reader is self)
    #pragma unroll
    for (int q = 0; q < 8; ++q) *(f32x4*)(dsth1 + q * 4) = h1v[q];
  }

  // ---- Stage D: s = softmax(h1 @ W_pool + b_pool); keep ssq ----
  float ssq = 0.f;
  {
    f32x4 s2v[4];
    #pragma unroll
    for (int q = 0; q < 4; ++q) s2v[q] = *(const f32x4*)(bpoolf + q * 4);
    #pragma unroll
    for (int m = 0; m < 32; ++m) {
      float hm = h1v[m >> 2][m & 3];
      const f32x4* wpm = (const f32x4*)(poolf + m * 16);
      #pragma unroll
      for (int q = 0; q < 4; ++q) s2v[q] += hm * wpm[q];
    }
    float s_[16];
    #pragma unroll
    for (int i = 0; i < 16; ++i) s_[i] = s2v[i >> 2][i & 3];
    float mx = s_[0];
    #pragma unroll
    for (int i = 1; i < 16; ++i) mx = fmaxf(mx, s_[i]);
    float sum = 0.f;
    #pragma unroll
    for (int i = 0; i < 16; ++i) { s_[i] = __expf(s_[i] - mx); sum += s_[i]; }
    float inv = 1.f / sum;
    #pragma unroll
    for (int i = 0; i < 16; ++i) { s_[i] *= inv; ssq += s_[i] * s_[i]; }
    float* srow = sbuf + t * 20;
    #pragma unroll
    for (int q = 0; q < 4; ++q) {
      f32x4 sv_ = { s_[4 * q], s_[4 * q + 1], s_[4 * q + 2], s_[4 * q + 3] };
      *(f32x4*)(srow + q * 4) = sv_;
    }
  }
  __syncthreads();

  // ---- P5: pass2  tA = A @ s; thread = 4 rows x 4 ch ----
  {
    f32x4 tacc[4] = {};
    const int cg4 = cg * 4;
    for (int v = 0; v < 256; ++v) {
      unsigned w = *(const unsigned int*)(smem + v * 260 + rg * 4);
      f32x4 sv = *(const f32x4*)(sbuf + v * 20 + cg4);
      #pragma unroll
      for (int r = 0; r < 4; ++r) {
        float cf = (float)((w >> (8 * r)) & 255u);
        tacc[r] += cf * sv;
      }
    }
    #pragma unroll
    for (int r = 0; r < 4; ++r) *(f32x4*)(tabuf + (4 * rg + r) * 20 + cg4) = tacc[r];
  }
  __syncthreads();   // adjacency dead from here

  // ---- P6: degree out, FG weights in, fused rank-256 reductions ----
  if (cg == 0) {
    #pragma unroll
    for (int r = 0; r < 4; ++r) degb[4 * rg + r] = dg[r];
  }
  for (int i = t; i < 1024; i += 256) rel2f[i] = ldf(P.wr2, i, BF);
  if (t < 32) brel2f[t] = ldf(P.br2, t, BF);
  for (int i = t; i < 1024; i += 256) root2f[i] = ldf(P.wro2, i, BF);
  for (int i = t; i < 1024; i += 256) lin2f[i] = ldf(P.wl2, i, BF);
  if (t < 32) blin2f[t] = ldf(P.bl2, t, BF);
  for (int i = t; i < 320; i += 256) lin3f[i] = ldf(P.wl3, i, BF);
  if (t < 10) blin3f[t] = ldf(P.bl3, t, BF);

  {
    const int kp = t >> 5, cp = t & 31, k3 = t >> 4, j3 = t & 15;
    float pa = 0.f, pb = 0.f, oa = 0.f, sa = 0.f;
    for (int n = 0; n < 256; ++n) {
      const float* srow = sbuf + n * 20;
      float s1 = srow[kp], s2a = srow[kp + 8], s3 = srow[k3], s4 = srow[j3];
      float hn = aggbuf[n * 36 + cp];   // h1
      float tn = tabuf[n * 20 + j3];    // (A s)
      pa += s1 * hn; pb += s2a * hn; oa += s3 * tn; sa += s3 * s4;
    }
    pbuf[kp * 32 + cp] = pa;
    pbuf[(kp + 8) * 32 + cp] = pb;
    oadjb[t] = oa;
    ssb[t] = sa;
  }
  __syncthreads();

  // ---- losses ----
  {
    float den = block_sum(degb[t] * ssq, scr, t);
    float num = block_sum((t < 16) ? oadjb[t * 17] : 0.f, scr, t);
    float fro = block_sum(ssb[t] * ssb[t], scr, t);
    float ssn = sqrtf(fro);
    float diag = ((t & 15) == (t >> 4)) ? 0.25f : 0.f;
    float term = ssb[t] / ssn - diag;
    float orth = block_sum(term * term, scr, t);
    if (t == 0) {
      atomicAdd(P.ws, -(num / den) * (1.f / NB));
      atomicAdd(P.ws + 1, sqrtf(orth) * (1.f / NB));
    }
  }
  __syncthreads();

  // ---- P7: normalize pooled adjacency ----
  if (t < 16) {
    float rs = 0.f;
    #pragma unroll
    for (int j = 0; j < 16; ++j) if (j != t) rs += oadjb[t * 16 + j];
    ddb[t] = sqrtf(rs) + 1e-15f;
  }
  __syncthreads();
  {
    int k = t >> 4, j = t & 15;
    float apv = (k == j) ? 0.f : oadjb[t] / (ddb[k] * ddb[j]);
    oadjb[t] = apv;          // own element only
  }
  __syncthreads();

  // ---- conv2 + readout + MLP + log_softmax ----
  {
    int k = t >> 5, c = t & 31;
    float q1 = 0.f, q2 = 0.f;
    #pragma unroll
    for (int j = 0; j < 16; ++j) {
      float pj = pbuf[j * 32 + c];
      q1 += oadjb[k * 16 + j] * pj;
      q2 += oadjb[(k + 8) * 16 + j] * pj;
    }
    qbuf[k * 32 + c] = q1; qbuf[(k + 8) * 32 + c] = q2;
  }
  __syncthreads();
  {
    int k = t >> 5, c = t & 31;
    float a1 = brel2f[c], a2 = a1;
    #pragma unroll
    for (int m = 0; m < 32; ++m) {
      float w1 = rel2f[m * 32 + c], w2 = root2f[m * 32 + c];
      a1 += qbuf[k * 32 + m] * w1 + pbuf[k * 32 + m] * w2;
      a2 += qbuf[(k + 8) * 32 + m] * w1 + pbuf[(k + 8) * 32 + m] * w2;
    }
    h2b[k * 32 + c] = a1; h2b[(k + 8) * 32 + c] = a2;
  }
  __syncthreads();
  if (t < 32) {
    float r = 0.f;
    #pragma unroll
    for (int k = 0; k < 16; ++k) r += h2b[k * 32 + t];
    rb[t] = r;
  }
  __syncthreads();
  if (t < 32) {
    float y = blin2f[t];
    #pragma unroll
    for (int m = 0; m < 32; ++m) y += rb[m] * lin2f[m * 32 + t];
    yb[t] = fmaxf(y, 0.f);
  }
  __syncthreads();
  if (t < 10) {
    float lg = blin3f[t];
    #pragma unroll
    for (int m = 0; m < 32; ++m) lg += yb[m] * lin3f[m * 10 + t];
    lgb[t] = lg;
  }
  __syncthreads();
  if (t == 0) {
    float mx = lgb[0];
    #pragma unroll
    for (int i = 1; i < 10; ++i) mx = fmaxf(mx, lgb[i]);
    float sum = 0.f;
    #pragma unroll
    for (int i = 0; i < 10; ++i) sum += __expf(lgb[i] - mx);
    lgb[10] = mx + __logf(sum);
  }
  __syncthreads();
  if (t < 10) {
    float val = lgb[t] - lgb[10];
    if (BF) ((unsigned short*)P.out)[b * 10 + t] = f2bf(val);
    else    P.out[b * 10 + t] = val;
  }
}

__global__ void mincut_fin(Params P) {
  if (threadIdx.x == 0) {
    const bool BF = detect_bf16(P.wr1);
    if (BF) {
      ((unsigned short*)P.out)[5120] = f2bf(P.ws[0]);
      ((unsigned short*)P.out)[5121] = f2bf(P.ws[1]);
    } else {
      P.out[5120] = P.ws[0];
      P.out[5121] = P.ws[1];
    }
  }
}

extern "C" void kernel_launch(void* const* d_in, const int* in_sizes, int n_in,
                              void* d_out, int out_size, void* d_ws, size_t ws_size,
                              hipStream_t stream) {
  (void)in_sizes; (void)n_in; (void)out_size; (void)ws_size;
  Params P;
  P.x    = d_in[0];
  P.ei   = d_in[1];
  P.wl1  = d_in[3];
  P.bl1  = d_in[4];
  P.wr1  = d_in[5];
  P.br1  = d_in[6];
  P.wro1 = d_in[7];
  P.wp   = d_in[8];
  P.bp   = d_in[9];
  P.wr2  = d_in[10];
  P.br2  = d_in[11];
  P.wro2 = d_in[12];
  P.wl2  = d_in[13];
  P.bl2  = d_in[14];
  P.wl3  = d_in[15];
  P.bl3  = d_in[16];
  P.out  = (float*)d_out;
  P.ws   = (float*)d_ws;

  hipMemsetAsync(d_ws, 0, 2 * sizeof(float), stream);
  hipFuncSetAttribute(reinterpret_cast<const void*>(mincut_main),
                      hipFuncAttributeMaxDynamicSharedMemorySize, SMEM_TOTAL);
  hipLaunchKernelGGL(mincut_main, dim3(NB), dim3(256), SMEM_TOTAL, stream, P);
  hipLaunchKernelGGL(mincut_fin, dim3(1), dim3(64), 0, stream, P);
}

// Round 3
// 299.895 us; speedup vs baseline: 1.1610x; 1.1610x over previous
//
#include <hip/hip_runtime.h>

#define NB 512
#define NN 256
#define EPG 8192
#define FINC 128

typedef float f32x4 __attribute__((ext_vector_type(4)));

__device__ __forceinline__ float bf2f(unsigned short u) {
  union { unsigned int i; float f; } x; x.i = ((unsigned int)u) << 16; return x.f;
}
__device__ __forceinline__ unsigned short f2bf(float f) {
  union { float f; unsigned int i; } x; x.f = f;
  unsigned int r = x.i + 0x7fffu + ((x.i >> 16) & 1u);
  return (unsigned short)(r >> 16);
}

struct Params {
  const void* x; const void* ei;
  const void *wl1, *bl1, *wr1, *br1, *wro1, *wp, *bp;
  const void *wr2, *br2, *wro2, *wl2, *bl2, *wl3, *bl3;
  float* out; float* ws;
};

// dtype probes (block-uniform); see round-1 notes.
__device__ __forceinline__ bool detect_bf16(const void* p) {
  const unsigned short* pw = (const unsigned short*)p;
  int sane = 0;
  for (int i = 0; i < 64; ++i) {
    unsigned e = (pw[i] >> 7) & 0xFFu;
    sane += (e > 96u && e < 132u) ? 1 : 0;
  }
  return sane >= 56;
}
__device__ __forceinline__ bool detect_i64(const void* p) {
  const int* pi = (const int*)p + EPG;
  int ok = 0;
  for (int i = 0; i < 32; ++i) ok += (pi[i] >= 256 && pi[i] < 512) ? 1 : 0;
  return ok < 24;
}
__device__ __forceinline__ float ldf(const void* p, int i, bool bf) {
  return bf ? bf2f(((const unsigned short*)p)[i]) : ((const float*)p)[i];
}

// ---- dynamic LDS layout (bytes) ----
// A  [0, 66560):      x staged bf16 (stride 260B) -> adj u8 col-major [v][u]
//                     (stride 260B) -> small-tail buffers + FG weights
// H0 [66560, 103424): h0 f32 stride 36f; after conv1 dead -> tA stride 20f
// W1 [103424,140288): lin1f+blin1f; after P1 dead -> agg/h1 f32 stride 36f
// S  [140288,160768): rel1f/root1f/brel1f (conv1); after conv1 -> s f32 stride 20f
// SC [160768,162944): poolf(512f) bpoolf(16f) scr(16f)
#define SMEM_TOTAL 162944

__device__ __forceinline__ float block_sum16(float v, float* scr, int t) {
  #pragma unroll
  for (int o = 32; o > 0; o >>= 1) v += __shfl_xor(v, o, 64);
  __syncthreads();
  if ((t & 63) == 0) scr[t >> 6] = v;
  __syncthreads();
  float s = 0.f;
  #pragma unroll
  for (int i = 0; i < 16; ++i) s += scr[i];
  return s;
}

__global__ __launch_bounds__(1024, 4) void mincut_main(Params P) {
  extern __shared__ char smem[];
  const int t = threadIdx.x;
  const int b = blockIdx.x;

  const bool BF  = detect_bf16(P.wr1);
  const bool I64 = detect_i64(P.ei);

  float* h0buf  = (float*)(smem + 66560);            // stride 36 f
  float* tabuf  = (float*)(smem + 66560);            // after conv1, stride 20 f
  float* aggbuf = (float*)(smem + 103424);           // agg then h1, stride 36 f
  float* lin1f  = (float*)(smem + 103424);
  float* blin1f = (float*)(smem + 103424 + 16384);
  float* rel1f  = (float*)(smem + 140288);           // conv1 weights (pre-s)
  float* root1f = (float*)(smem + 140288 + 4096);
  float* brel1f = (float*)(smem + 140288 + 8192);
  float* sbuf   = (float*)(smem + 140288);           // s, stride 20 f (post-conv1)
  float* poolf  = (float*)(smem + 160768);
  float* bpoolf = (float*)(smem + 160768 + 2048);
  float* scr    = (float*)(smem + 160768 + 2112);    // 16 f
  // region-A tail (valid only after adjacency is dead)
  float* pbuf   = (float*)(smem);            // 512 f
  float* oadjb  = (float*)(smem + 2048);     // 256 f
  float* ssb    = (float*)(smem + 3072);     // 256 f
  float* qbuf   = (float*)(smem + 4096);     // 512 f
  float* ddb    = (float*)(smem + 6144);     // 16 f
  float* h2b    = (float*)(smem + 6208);     // 512 f
  float* rb     = (float*)(smem + 8256);     // 32 f
  float* yb     = (float*)(smem + 8384);     // 32 f
  float* lgb    = (float*)(smem + 8512);     // 12 f
  float* degb   = (float*)(smem + 12288);    // 256 f
  float* ssqb   = (float*)(smem + 13312);    // 256 f
  float* rel2f  = (float*)(smem + 16384);
  float* brel2f = (float*)(smem + 20480);
  float* root2f = (float*)(smem + 20608);
  float* lin2f  = (float*)(smem + 24704);
  float* blin2f = (float*)(smem + 28800);
  float* lin3f  = (float*)(smem + 28928);
  float* blin3f = (float*)(smem + 30208);

  const int n4 = t >> 2;      // node / row for 4-lane-split stages
  const int q4 = t & 3;       // quad slice

  // ---- P0: stage lin1/pool weights (f32) + x (bf16, stride 260B rows) ----
  for (int i = t; i < 4096; i += 1024) lin1f[i] = ldf(P.wl1, i, BF);
  if (t < 32) blin1f[t] = ldf(P.bl1, t, BF);
  if (t < 512) poolf[t] = ldf(P.wp, t, BF);
  if (t < 16) bpoolf[t] = ldf(P.bp, t, BF);
  if (BF) {
    const unsigned short* gx = (const unsigned short*)P.x + (size_t)b * (NN * FINC);
    #pragma unroll
    for (int it = 0; it < 4; ++it) {
      int g = (it * 1024 + t) * 8;
      int n = g >> 7, k = g & 127;
      uint4 val = *(const uint4*)(gx + g);
      unsigned int* dst = (unsigned int*)(smem + n * 260 + k * 2);
      dst[0] = val.x; dst[1] = val.y; dst[2] = val.z; dst[3] = val.w;
    }
  } else {
    const float* gx = (const float*)P.x + (size_t)b * (NN * FINC);
    #pragma unroll
    for (int it = 0; it < 4; ++it) {
      int g = (it * 1024 + t) * 8;
      int n = g >> 7, k = g & 127;
      float4 v0 = *(const float4*)(gx + g);
      float4 v1 = *(const float4*)(gx + g + 4);
      unsigned int* dst = (unsigned int*)(smem + n * 260 + k * 2);
      dst[0] = (unsigned)f2bf(v0.x) | ((unsigned)f2bf(v0.y) << 16);
      dst[1] = (unsigned)f2bf(v0.z) | ((unsigned)f2bf(v0.w) << 16);
      dst[2] = (unsigned)f2bf(v1.x) | ((unsigned)f2bf(v1.y) << 16);
      dst[3] = (unsigned)f2bf(v1.z) | ((unsigned)f2bf(v1.w) << 16);
    }
  }
  __syncthreads();

  // ---- P1: h0 = x @ W_lin1 + b ; 4 lanes per node, 8 ch each ----
  {
    f32x4 a0 = *(const f32x4*)(blin1f + q4 * 8);
    f32x4 a1 = *(const f32x4*)(blin1f + q4 * 8 + 4);
    const unsigned short* xrow = (const unsigned short*)(smem + n4 * 260);
    const float* wbase = lin1f + q4 * 8;
    for (int k = 0; k < FINC; ++k) {
      float xv = bf2f(xrow[k]);
      const f32x4* wr = (const f32x4*)(wbase + k * 32);
      a0 += xv * wr[0];
      a1 += xv * wr[1];
    }
    float* dst = h0buf + n4 * 36 + q4 * 8;
    *(f32x4*)dst = a0;
    *(f32x4*)(dst + 4) = a1;
  }
  __syncthreads();

  // ---- P2: zero adjacency region (66560 B) ----
  {
    uint4 z = {0u, 0u, 0u, 0u};
    for (int i = t; i < 4160; i += 1024) ((uint4*)smem)[i] = z;
  }
  __syncthreads();

  // ---- P3: build u8 adjacency, col-major [v][u], packed-byte atomics ----
  if (I64) {
    const long long* es = (const long long*)P.ei + (size_t)b * EPG;
    const long long* ed = (const long long*)P.ei + (size_t)NB * EPG + (size_t)b * EPG;
    #pragma unroll
    for (int i2 = 0; i2 < EPG / 1024; ++i2) {
      int e = i2 * 1024 + t;
      int u = ((int)es[e]) & 255;
      int v = ((int)ed[e]) & 255;
      unsigned idx = (unsigned)(v * 260 + u);
      atomicAdd((unsigned int*)(smem + (idx & ~3u)), 1u << ((idx & 3u) * 8u));
    }
  } else {
    const int* es = (const int*)P.ei + (size_t)b * EPG;
    const int* ed = (const int*)P.ei + (size_t)NB * EPG + (size_t)b * EPG;
    #pragma unroll
    for (int i2 = 0; i2 < EPG / 1024; ++i2) {
      int e = i2 * 1024 + t;
      int u = es[e] & 255;
      int v = ed[e] & 255;
      unsigned idx = (unsigned)(v * 260 + u);
      atomicAdd((unsigned int*)(smem + (idx & ~3u)), 1u << ((idx & 3u) * 8u));
    }
  }
  __syncthreads();

  // ---- P4: agg = A @ h0 (+ degree); thread = 1 row (n4) x 8 ch (q4) ----
  float dg = 0.f;
  {
    f32x4 acc0 = {0.f, 0.f, 0.f, 0.f}, acc1 = {0.f, 0.f, 0.f, 0.f};
    const char* wcol = smem + (n4 >> 2) * 4;
    const int sh = (n4 & 3) * 8;
    const float* hb = h0buf + q4 * 8;
    #pragma unroll 2
    for (int v = 0; v < 256; ++v) {
      unsigned w = *(const unsigned int*)(wcol + v * 260);
      float cf = (float)((w >> sh) & 255u);
      const f32x4* hv = (const f32x4*)(hb + v * 36);
      dg += cf;
      acc0 += cf * hv[0];
      acc1 += cf * hv[1];
    }
    float* dstp = aggbuf + n4 * 36 + q4 * 8;
    *(f32x4*)dstp = acc0;
    *(f32x4*)(dstp + 4) = acc1;
  }
  // conv1 weights into S region (s not yet written)
  rel1f[t] = ldf(P.wr1, t, BF);
  root1f[t] = ldf(P.wro1, t, BF);
  if (t < 32) brel1f[t] = ldf(P.br1, t, BF);
  __syncthreads();

  // ---- Stage C: h1 = agg @ W_rel1 + b_rel1 + h0 @ W_root1 ; 4 lanes/node ----
  {
    f32x4 h1a = *(const f32x4*)(brel1f + q4 * 8);
    f32x4 h1b = *(const f32x4*)(brel1f + q4 * 8 + 4);
    const float* arow = aggbuf + n4 * 36;
    const float* hrow = h0buf + n4 * 36;
    const float* wrb = rel1f + q4 * 8;
    const float* wob = root1f + q4 * 8;
    #pragma unroll
    for (int kq = 0; kq < 8; ++kq) {
      f32x4 av = *(const f32x4*)(arow + kq * 4);
      f32x4 bv = *(const f32x4*)(hrow + kq * 4);
      #pragma unroll
      for (int j = 0; j < 4; ++j) {
        int k = kq * 4 + j;
        const f32x4* wr = (const f32x4*)(wrb + k * 32);
        const f32x4* wo = (const f32x4*)(wob + k * 32);
        h1a += av[j] * wr[0] + bv[j] * wo[0];
        h1b += av[j] * wr[1] + bv[j] * wo[1];
      }
    }
    float* dsth1 = aggbuf + n4 * 36 + q4 * 8;   // overwrite own agg slice (readers = same quad, same wave)
    *(f32x4*)dsth1 = h1a;
    *(f32x4*)(dsth1 + 4) = h1b;
  }
  __syncthreads();   // conv1 weights dead; S region becomes s

  // ---- Stage D: s = softmax(h1 @ W_pool + b_pool); quad-shuffle softmax ----
  float ssq;
  {
    f32x4 sv = *(const f32x4*)(bpoolf + q4 * 4);
    const float* hrow = aggbuf + n4 * 36;
    const float* wpb = poolf + q4 * 4;
    #pragma unroll 8
    for (int m = 0; m < 32; ++m) {
      float hm = hrow[m];
      sv += hm * *(const f32x4*)(wpb + m * 16);
    }
    float mx = fmaxf(fmaxf(sv[0], sv[1]), fmaxf(sv[2], sv[3]));
    mx = fmaxf(mx, __shfl_xor(mx, 1, 64));
    mx = fmaxf(mx, __shfl_xor(mx, 2, 64));
    #pragma unroll
    for (int i = 0; i < 4; ++i) sv[i] = __expf(sv[i] - mx);
    float sm = sv[0] + sv[1] + sv[2] + sv[3];
    sm += __shfl_xor(sm, 1, 64);
    sm += __shfl_xor(sm, 2, 64);
    float inv = 1.f / sm;
    #pragma unroll
    for (int i = 0; i < 4; ++i) sv[i] *= inv;
    float sq = sv[0] * sv[0] + sv[1] * sv[1] + sv[2] * sv[2] + sv[3] * sv[3];
    sq += __shfl_xor(sq, 1, 64);
    sq += __shfl_xor(sq, 2, 64);
    ssq = sq;
    *(f32x4*)(sbuf + n4 * 20 + q4 * 4) = sv;
  }
  __syncthreads();

  // ---- P5: tA = A @ s ; thread = 1 row (n4) x 4 ch (q4); tA overlays dead h0 ----
  {
    f32x4 tacc = {0.f, 0.f, 0.f, 0.f};
    const char* wcol = smem + (n4 >> 2) * 4;
    const int sh = (n4 & 3) * 8;
    const float* sb = sbuf + q4 * 4;
    #pragma unroll 2
    for (int v = 0; v < 256; ++v) {
      unsigned w = *(const unsigned int*)(wcol + v * 260);
      float cf = (float)((w >> sh) & 255u);
      tacc += cf * *(const f32x4*)(sb + v * 20);
    }
    *(f32x4*)(tabuf + n4 * 20 + q4 * 4) = tacc;
  }
  __syncthreads();   // adjacency dead from here

  // ---- P6: persist deg/ssq, stage FG weights, fused rank-256 reductions ----
  if (q4 == 0) { degb[n4] = dg; ssqb[n4] = ssq; }
  rel2f[t] = ldf(P.wr2, t, BF);
  if (t < 32) brel2f[t] = ldf(P.br2, t, BF);
  root2f[t] = ldf(P.wro2, t, BF);
  lin2f[t] = ldf(P.wl2, t, BF);
  if (t < 32) blin2f[t] = ldf(P.bl2, t, BF);
  if (t < 320) lin3f[t] = ldf(P.wl3, t, BF);
  if (t < 10) blin3f[t] = ldf(P.bl3, t, BF);

  if (t < 512) {
    const int kp = t >> 5, cp = t & 31;
    float pa = 0.f;
    for (int n = 0; n < 256; ++n) pa += sbuf[n * 20 + kp] * aggbuf[n * 36 + cp];
    pbuf[kp * 32 + cp] = pa;
  } else if (t < 768) {
    const int i = t - 512, k3 = i >> 4, j3 = i & 15;
    float oa = 0.f;
    for (int n = 0; n < 256; ++n) oa += sbuf[n * 20 + k3] * tabuf[n * 20 + j3];
    oadjb[i] = oa;
  } else {
    const int i = t - 768, k3 = i >> 4, j3 = i & 15;
    float sa = 0.f;
    for (int n = 0; n < 256; ++n) sa += sbuf[n * 20 + k3] * sbuf[n * 20 + j3];
    ssb[i] = sa;
  }
  __syncthreads();

  // ---- losses ----
  {
    float den = block_sum16((t < 256) ? degb[t] * ssqb[t] : 0.f, scr, t);
    float num = block_sum16((t < 16) ? oadjb[t * 17] : 0.f, scr, t);
    float fro = block_sum16((t < 256) ? ssb[t] * ssb[t] : 0.f, scr, t);
    float ssn = sqrtf(fro);
    float term = 0.f;
    if (t < 256) {
      float diag = ((t & 15) == (t >> 4)) ? 0.25f : 0.f;
      term = ssb[t] / ssn - diag;
    }
    float orth = block_sum16(term * term, scr, t);
    if (t == 0) {
      atomicAdd(P.ws, -(num / den) * (1.f / NB));
      atomicAdd(P.ws + 1, sqrtf(orth) * (1.f / NB));
    }
  }
  __syncthreads();

  // ---- P7: normalize pooled adjacency ----
  if (t < 16) {
    float rs = 0.f;
    #pragma unroll
    for (int j = 0; j < 16; ++j) if (j != t) rs += oadjb[t * 16 + j];
    ddb[t] = sqrtf(rs) + 1e-15f;
  }
  __syncthreads();
  if (t < 256) {
    int k = t >> 4, j = t & 15;
    float apv = (k == j) ? 0.f : oadjb[t] / (ddb[k] * ddb[j]);
    oadjb[t] = apv;
  }
  __syncthreads();

  // ---- conv2 + readout + MLP + log_softmax ----
  if (t < 512) {
    int k = t >> 5, c = t & 31;
    float q = 0.f;
    #pragma unroll
    for (int j = 0; j < 16; ++j) q += oadjb[k * 16 + j] * pbuf[j * 32 + c];
    qbuf[k * 32 + c] = q;
  }
  __syncthreads();
  if (t < 512) {
    int k = t >> 5, c = t & 31;
    float a1 = brel2f[c];
    #pragma unroll
    for (int m = 0; m < 32; ++m)
      a1 += qbuf[k * 32 + m] * rel2f[m * 32 + c] + pbuf[k * 32 + m] * root2f[m * 32 + c];
    h2b[k * 32 + c] = a1;
  }
  __syncthreads();
  if (t < 32) {
    float r = 0.f;
    #pragma unroll
    for (int k = 0; k < 16; ++k) r += h2b[k * 32 + t];
    rb[t] = r;
  }
  __syncthreads();
  if (t < 32) {
    float y = blin2f[t];
    #pragma unroll
    for (int m = 0; m < 32; ++m) y += rb[m] * lin2f[m * 32 + t];
    yb[t] = fmaxf(y, 0.f);
  }
  __syncthreads();
  if (t < 10) {
    float lg = blin3f[t];
    #pragma unroll
    for (int m = 0; m < 32; ++m) lg += yb[m] * lin3f[m * 10 + t];
    lgb[t] = lg;
  }
  __syncthreads();
  if (t == 0) {
    float mx = lgb[0];
    #pragma unroll
    for (int i = 1; i < 10; ++i) mx = fmaxf(mx, lgb[i]);
    float sum = 0.f;
    #pragma unroll
    for (int i = 0; i < 10; ++i) sum += __expf(lgb[i] - mx);
    lgb[10] = mx + __logf(sum);
  }
  __syncthreads();
  if (t < 10) {
    float val = lgb[t] - lgb[10];
    if (BF) ((unsigned short*)P.out)[b * 10 + t] = f2bf(val);
    else    P.out[b * 10 + t] = val;
  }
}

__global__ void mincut_fin(Params P) {
  if (threadIdx.x == 0) {
    const bool BF = detect_bf16(P.wr1);
    if (BF) {
      ((unsigned short*)P.out)[5120] = f2bf(P.ws[0]);
      ((unsigned short*)P.out)[5121] = f2bf(P.ws[1]);
    } else {
      P.out[5120] = P.ws[0];
      P.out[5121] = P.ws[1];
    }
  }
}

extern "C" void kernel_launch(void* const* d_in, const int* in_sizes, int n_in,
                              void* d_out, int out_size, void* d_ws, size_t ws_size,
                              hipStream_t stream) {
  (void)in_sizes; (void)n_in; (void)out_size; (void)ws_size;
  Params P;
  P.x    = d_in[0];
  P.ei   = d_in[1];
  P.wl1  = d_in[3];
  P.bl1  = d_in[4];
  P.wr1  = d_in[5];
  P.br1  = d_in[6];
  P.wro1 = d_in[7];
  P.wp   = d_in[8];
  P.bp   = d_in[9];
  P.wr2  = d_in[10];
  P.br2  = d_in[11];
  P.wro2 = d_in[12];
  P.wl2  = d_in[13];
  P.bl2  = d_in[14];
  P.wl3  = d_in[15];
  P.bl3  = d_in[16];
  P.out  = (float*)d_out;
  P.ws   = (float*)d_ws;

  hipMemsetAsync(d_ws, 0, 2 * sizeof(float), stream);
  hipFuncSetAttribute(reinterpret_cast<const void*>(mincut_main),
                      hipFuncAttributeMaxDynamicSharedMemorySize, SMEM_TOTAL);
  hipLaunchKernelGGL(mincut_main, dim3(NB), dim3(1024), SMEM_TOTAL, stream, P);
  hipLaunchKernelGGL(mincut_fin, dim3(1), dim3(64), 0, stream, P);
}